// Round 2
// baseline (1213.387 us; speedup 1.0000x reference)
//
#include <hip/hip_runtime.h>
#include <hip/hip_bf16.h>

// Model dims (fixed by the reference)
#define BB 16
#define LL 256
#define DD 768
#define HH 12
#define HDD 64
#define NLL 4
#define FF 3072
#define EE 50
#define QKVS 2304            // fused q|k|v row stride
#define TOKD ((size_t)BB * LL * DD)   // 3,145,728

typedef unsigned short ushort_t;
typedef __bf16 bf16x8 __attribute__((ext_vector_type(8)));
typedef float f32x4 __attribute__((ext_vector_type(4)));

__device__ __forceinline__ float b2f(ushort_t u) {
    union { unsigned int i; float f; } x; x.i = ((unsigned int)u) << 16; return x.f;
}
__device__ __forceinline__ ushort_t f2b(float f) {
    unsigned int u = __builtin_bit_cast(unsigned int, f);
    unsigned int r = u + 0x7fffu + ((u >> 16) & 1u);   // RNE
    return (ushort_t)(r >> 16);
}

__device__ __forceinline__ void gl2lds16(const void* g, void* l) {
    __builtin_amdgcn_global_load_lds(
        (const __attribute__((address_space(1))) unsigned int*)g,
        (__attribute__((address_space(3))) unsigned int*)l,
        16, 0, 0);
}

// ---------------- fused transpose + fp32->bf16: out[C,R] = bf16(in[R,C]^T), batched over z ----------------
__global__ __launch_bounds__(256) void transpose_f2b(
    const float* __restrict__ in, ushort_t* __restrict__ out, int R, int C,
    long inZ, long outZ)
{
    __shared__ ushort_t tile[32][33];
    in  += (long)blockIdx.z * inZ;
    out += (long)blockIdx.z * outZ;
    int c0 = blockIdx.x * 32, r0 = blockIdx.y * 32;
    int tx = threadIdx.x, ty = threadIdx.y; // (32,8)
#pragma unroll
    for (int i = 0; i < 32; i += 8)
        tile[ty + i][tx] = f2b(in[(long)(r0 + ty + i) * C + c0 + tx]);
    __syncthreads();
#pragma unroll
    for (int i = 0; i < 32; i += 8)
        out[(long)(c0 + ty + i) * R + r0 + tx] = tile[tx][ty + i];
}

// ---------------- concat bq|bk|bv for layer l into float[2304] ----------------
__global__ __launch_bounds__(256) void fuse_bias_kernel(
    const float* __restrict__ bq, const float* __restrict__ bk,
    const float* __restrict__ bv, int l, float* __restrict__ out)
{
    int n = blockIdx.x * 256 + threadIdx.x;
    if (n >= QKVS) return;
    float v = (n < DD) ? bq[l * DD + n]
            : (n < 2 * DD) ? bk[l * DD + n - DD]
            : bv[l * DD + n - 2 * DD];
    out[n] = v;
}

// ---------------- embedding + sinusoidal pos ----------------
__global__ __launch_bounds__(256) void embed_kernel(
    const int* __restrict__ wids, const float* __restrict__ wemb,
    float* __restrict__ hf, ushort_t* __restrict__ hb)
{
    long idx = (long)blockIdx.x * 256 + threadIdx.x; // < 4096*768
    int d = (int)(idx % DD);
    int t = (int)(idx / DD);
    int lpos = t & (LL - 1);
    int wid = wids[t];
    float freq = expf(-9.210340371976184f * (float)(d & ~1) * (1.f / (float)DD));
    float ang = (float)lpos * freq;
    float pe = (d & 1) ? cosf(ang) : sinf(ang);
    float hv = wemb[(long)wid * DD + d] + pe;
    hf[idx] = hv;
    hb[idx] = f2b(hv);
}

// ---------------- bf16 MFMA GEMM with optional split-K over blockIdx.z ----------------
// C[M,N] = A[M,K] @ Bt[N,K]^T (+ bias on z==0). Slice z covers k in [z*Ksl, (z+1)*Ksl).
// fp32 output goes to outf + z*M*N (partials summed later). 128x128 tile, BK=32.
// T4 pipeline: 3 LDS buffers, depth-2 prefetch, counted s_waitcnt vmcnt(4) —
// vmcnt NEVER drains to 0 in the main loop (last iter peeled). One raw s_barrier
// per K-step. Buffer-reuse safety: stage(kt+2) overwrites tile kt-1's buffer,
// whose reads were lgkm-drained by every wave before MFMA(kt-1), which precedes
// barrier(kt); the stage is issued after barrier(kt).
__global__ __launch_bounds__(256) void gemm_bf16(
    const ushort_t* __restrict__ A, const ushort_t* __restrict__ Bt,
    const float* __restrict__ bias,
    ushort_t* __restrict__ outb, float* __restrict__ outf,
    int M, int N, int K, int Ksl, int relu)
{
    __shared__ __align__(16) ushort_t As[3][128 * 32];
    __shared__ __align__(16) ushort_t Bs[3][128 * 32];
    const int tid = threadIdx.x;
    const int wave = tid >> 6, lane = tid & 63;
    const int quad = lane >> 4, l16 = lane & 15;
    const int m0 = blockIdx.y * 128, n0 = blockIdx.x * 128;
    const int z = blockIdx.z;
    const int kbase = z * Ksl;
    const int wm = (wave >> 1) * 64, wn = (wave & 1) * 64;
    const ushort_t* Ab = A + (long)m0 * K;
    const ushort_t* Bb = Bt + (long)n0 * K;

    // staging geometry: chunk c = tid + i*256 covers (row = c>>2, kc = (c&3)*8);
    // LDS linear dest byte = c*16 = wave*1024 + i*4096 (+ lane*16 implicit in HW).
    const int srow = tid >> 2, skc = (tid & 3) * 8;

    f32x4 acc[4][4];
#pragma unroll
    for (int mi = 0; mi < 4; ++mi)
#pragma unroll
        for (int ni = 0; ni < 4; ++ni) acc[mi][ni] = (f32x4){0.f, 0.f, 0.f, 0.f};

    const int nk = Ksl >> 5;

    // 4 VMEM instructions per stage per wave (2 A + 2 B)
    auto stage = [&](int kt, ushort_t* Ad, ushort_t* Bd) {
        const int k0 = kbase + (kt << 5);
        const ushort_t* ga = &Ab[(long)srow * K + k0 + skc];
        const ushort_t* gb = &Bb[(long)srow * K + k0 + skc];
        char* la = (char*)Ad + wave * 1024;
        char* lb = (char*)Bd + wave * 1024;
        gl2lds16(ga, la);
        gl2lds16(gb, lb);
        gl2lds16(ga + (long)64 * K, la + 4096);
        gl2lds16(gb + (long)64 * K, lb + 4096);
    };

    ushort_t *A0 = As[0], *A1 = As[1], *A2 = As[2];
    ushort_t *B0 = Bs[0], *B1 = Bs[1], *B2 = Bs[2];

    stage(0, A0, B0);
    stage(1, A1, B1);

    for (int kt = 0; kt < nk; ++kt) {
        if (kt + 1 < nk) {
            // tile kt's 4 loads landed; tile kt+1's 4 may remain in flight
            asm volatile("s_waitcnt vmcnt(4)" ::: "memory");
        } else {
            // final tile: nothing staged after it, must drain
            asm volatile("s_waitcnt vmcnt(0)" ::: "memory");
        }
        __builtin_amdgcn_s_barrier();
        __builtin_amdgcn_sched_barrier(0);
        // prefetch tile kt+2 into the buffer vacated by tile kt-1
        if (kt + 2 < nk) stage(kt + 2, A2, B2);
        bf16x8 af[4], bfr[4];
#pragma unroll
        for (int t = 0; t < 4; ++t)
            af[t] = *(const bf16x8*)&A0[(wm + t * 16 + l16) * 32 + quad * 8];
#pragma unroll
        for (int t = 0; t < 4; ++t)
            bfr[t] = *(const bf16x8*)&B0[(wn + t * 16 + l16) * 32 + quad * 8];
#pragma unroll
        for (int mi = 0; mi < 4; ++mi)
#pragma unroll
            for (int ni = 0; ni < 4; ++ni)
                acc[mi][ni] = __builtin_amdgcn_mfma_f32_16x16x32_bf16(
                    af[mi], bfr[ni], acc[mi][ni], 0, 0, 0);
        // rotate buffers: cur <- next <- free <- cur
        ushort_t* ta = A0; A0 = A1; A1 = A2; A2 = ta;
        ushort_t* tb = B0; B0 = B1; B1 = B2; B2 = tb;
    }

    float* outfz = outf ? outf + (size_t)z * M * N : nullptr;
#pragma unroll
    for (int ni = 0; ni < 4; ++ni) {
        int col = n0 + wn + ni * 16 + l16;
        float bv = (bias && z == 0) ? bias[col] : 0.f;
#pragma unroll
        for (int mi = 0; mi < 4; ++mi) {
#pragma unroll
            for (int r = 0; r < 4; ++r) {
                int row = m0 + wm + mi * 16 + quad * 4 + r;
                float vv = acc[mi][ni][r] + bv;
                if (relu) vv = fmaxf(vv, 0.f);
                if (outb) outb[(long)row * N + col] = f2b(vv);
                if (outfz) outfz[(long)row * N + col] = vv;
            }
        }
    }
}

// ---------------- MFMA attention (fused qkv input, stride 2304) ----------------
#define QS_STR 72
#define VT_STR 264
#define P_STR  264
#define S_STR  257
#define PE_STR 53

__global__ __launch_bounds__(256) void attn_kernel(
    const ushort_t* __restrict__ qkv,
    const int* __restrict__ adjm, const int* __restrict__ etyp,
    const float* __restrict__ eemb, ushort_t* __restrict__ out)
{
    __shared__ __align__(16) char smem[64448];
    ushort_t* VT = (ushort_t*)smem;                         // 64 x 264 bf16
    float*    S  = (float*)(smem + 33792);                  // 16 x 257 f32
    ushort_t* P  = (ushort_t*)(smem + 50240);               // 16 x 264 bf16
    float*    Pe = (float*)(smem + 58688);                  // 16 x 53 f32
    char*     U  = smem + 62080;                            // union: Qs / red
    float* invrow = (float*)(smem + 64384);                 // 16 f32
    ushort_t* Qs = (ushort_t*)U;                            // 16 x 72 bf16
    float*    red = (float*)U;                              // [2][16][17]

    const int blk = blockIdx.x;
    const int qt = blk & 15;
    const int h  = (blk >> 4) % HH;
    const int b  = blk / (16 * HH);
    const int i0 = qt * 16;
    const int tid = threadIdx.x;
    const int wave = tid >> 6, lane = tid & 63;
    const int quad = lane >> 4, l16 = lane & 15;

    // ---- stage Qs (16x64) and VT (64x256, transposed) ----
    if (tid < 128) {
        int row = tid >> 3, d0 = (tid & 7) * 8;
        *(int4*)&Qs[row * QS_STR + d0] =
            *(const int4*)&qkv[((long)(b * LL + i0 + row)) * QKVS + h * HDD + d0];
    }
#pragma unroll
    for (int i = 0; i < 8; ++i) {
        int c = tid + i * 256;           // 2048 chunks
        int j = c >> 3, d0 = (c & 7) * 8;
        int4 raw = *(const int4*)&qkv[((long)(b * LL + j)) * QKVS + 2 * DD + h * HDD + d0];
        const ushort_t* vals = (const ushort_t*)&raw;
#pragma unroll
        for (int u = 0; u < 8; ++u) VT[(d0 + u) * VT_STR + j] = vals[u];
    }
    __syncthreads();

    // ---- phase 1: Pe = Q @ E^T ----
    {
        int e = wave * 16 + l16;
        f32x4 acc = (f32x4){0.f, 0.f, 0.f, 0.f};
#pragma unroll
        for (int kk = 0; kk < 2; ++kk) {
            bf16x8 af = *(const bf16x8*)&Qs[l16 * QS_STR + kk * 32 + quad * 8];
            bf16x8 bf = (bf16x8){0, 0, 0, 0, 0, 0, 0, 0};
            if (e < EE) {
                const float* ep = &eemb[(long)e * HDD + kk * 32 + quad * 8];
#pragma unroll
                for (int u = 0; u < 8; ++u) bf[u] = (__bf16)ep[u];
            }
            acc = __builtin_amdgcn_mfma_f32_16x16x32_bf16(af, bf, acc, 0, 0, 0);
        }
        if (e < EE) {
#pragma unroll
            for (int r = 0; r < 4; ++r) Pe[(quad * 4 + r) * PE_STR + e] = acc[r];
        }
    }

    // ---- phase 2: S = Q @ K^T (K B-frags straight from global, L2-hot) ----
#pragma unroll
    for (int jt = 0; jt < 4; ++jt) {
        int jtile = wave * 4 + jt;
        int j = jtile * 16 + l16;
        f32x4 acc = (f32x4){0.f, 0.f, 0.f, 0.f};
#pragma unroll
        for (int kk = 0; kk < 2; ++kk) {
            bf16x8 af = *(const bf16x8*)&Qs[l16 * QS_STR + kk * 32 + quad * 8];
            bf16x8 bf = *(const bf16x8*)&qkv[((long)(b * LL + j)) * QKVS + DD + h * HDD + kk * 32 + quad * 8];
            acc = __builtin_amdgcn_mfma_f32_16x16x32_bf16(af, bf, acc, 0, 0, 0);
        }
#pragma unroll
        for (int r = 0; r < 4; ++r)
            S[(quad * 4 + r) * S_STR + jtile * 16 + l16] = acc[r];
    }
    __syncthreads();

    // ---- phase 3: masked softmax with edge gather ----
    {
        const int row = tid & 15, seg = tid >> 4;
        const int i = i0 + row;
        const int* etp = etyp + ((long)(b * LL + i)) * LL + seg * 16;
        const int* adp = adjm + ((long)(b * LL + i)) * LL + seg * 16;
        int etv[16], adv[16];
#pragma unroll
        for (int t = 0; t < 4; ++t) {
            *(int4*)&etv[t * 4] = *(const int4*)&etp[t * 4];
            *(int4*)&adv[t * 4] = *(const int4*)&adp[t * 4];
        }
        float vals[16];
        float pmax = -1e30f;
#pragma unroll
        for (int c = 0; c < 16; ++c) {
            float s = S[row * S_STR + seg * 16 + c];
            float pe = Pe[row * PE_STR + etv[c]];
            float vv = adv[c] ? (s + pe) * 0.125f : -1e30f;
            vals[c] = vv;
            pmax = fmaxf(pmax, vv);
        }
        red[row * 17 + seg] = pmax;
        __syncthreads();
        float m = -1e30f;
#pragma unroll
        for (int g = 0; g < 16; ++g) m = fmaxf(m, red[row * 17 + g]);
        float sum = 0.f;
#pragma unroll
        for (int c = 0; c < 16; ++c) {
            float p = __expf(vals[c] - m);
            ushort_t pb = f2b(p);
            sum += b2f(pb);
            P[row * P_STR + seg * 16 + c] = pb;
        }
        red[272 + row * 17 + seg] = sum;
        __syncthreads();
        if (tid < 16) {
            float tot = 0.f;
#pragma unroll
            for (int g = 0; g < 16; ++g) tot += red[272 + tid * 17 + g];
            invrow[tid] = 1.f / tot;
        }
        __syncthreads();
    }

    // ---- phase 4: O = P @ V ----
    {
        f32x4 acc = (f32x4){0.f, 0.f, 0.f, 0.f};
#pragma unroll
        for (int kt = 0; kt < 8; ++kt) {
            bf16x8 af = *(const bf16x8*)&P[l16 * P_STR + kt * 32 + quad * 8];
            bf16x8 bf = *(const bf16x8*)&VT[(wave * 16 + l16) * VT_STR + kt * 32 + quad * 8];
            acc = __builtin_amdgcn_mfma_f32_16x16x32_bf16(af, bf, acc, 0, 0, 0);
        }
#pragma unroll
        for (int r = 0; r < 4; ++r) {
            int row = quad * 4 + r;
            float ov = acc[r] * invrow[row];
            out[((long)(b * LL + i0 + row)) * DD + h * HDD + wave * 16 + l16] = f2b(ov);
        }
    }
}

// ---------------- residual + layernorm; sums nparts split-K partials ----------------
__global__ __launch_bounds__(256) void ln_kernel(
    float* __restrict__ hf, ushort_t* __restrict__ hb,
    const float* __restrict__ proj, int nparts,
    const float* __restrict__ g, const float* __restrict__ be)
{
    const int r = blockIdx.x, tid = threadIdx.x;
    const long rb = (long)r * DD;
    float x[3];
#pragma unroll
    for (int i = 0; i < 3; ++i) {
        int d = tid + i * 256;
        float t = hf[rb + d];
        for (int p = 0; p < nparts; ++p) t += proj[(size_t)p * TOKD + rb + d];
        x[i] = t;
    }
    float s = x[0] + x[1] + x[2];
    float s2 = x[0] * x[0] + x[1] * x[1] + x[2] * x[2];
#pragma unroll
    for (int o = 1; o < 64; o <<= 1) { s += __shfl_xor(s, o); s2 += __shfl_xor(s2, o); }
    __shared__ float rs[4], rq[4];
    int wave = tid >> 6;
    if ((tid & 63) == 0) { rs[wave] = s; rq[wave] = s2; }
    __syncthreads();
    float S  = rs[0] + rs[1] + rs[2] + rs[3];
    float S2 = rq[0] + rq[1] + rq[2] + rq[3];
    float mean = S * (1.f / (float)DD);
    float var  = S2 * (1.f / (float)DD) - mean * mean;
    float rstd = rsqrtf(var + 1e-5f);
#pragma unroll
    for (int i = 0; i < 3; ++i) {
        int d = tid + i * 256;
        float y = (x[i] - mean) * rstd * g[d] + be[d];
        hf[rb + d] = y;
        hb[rb + d] = f2b(y);
    }
}

// ---------------- classifier head ----------------
__global__ __launch_bounds__(256) void cls_kernel(
    const float* __restrict__ hf, const float* __restrict__ W,
    const float* __restrict__ bias, float* __restrict__ out)
{
    int b = blockIdx.x, tid = threadIdx.x;
    const float* hr = hf + (long)b * LL * DD;
    float p0 = 0.f, p1 = 0.f;
    for (int d = tid; d < DD; d += 256) {
        float hv = hr[d];
        p0 = fmaf(hv, W[d * 2 + 0], p0);
        p1 = fmaf(hv, W[d * 2 + 1], p1);
    }
#pragma unroll
    for (int o = 1; o < 64; o <<= 1) { p0 += __shfl_xor(p0, o); p1 += __shfl_xor(p1, o); }
    __shared__ float r0[4], r1[4];
    int wave = tid >> 6;
    if ((tid & 63) == 0) { r0[wave] = p0; r1[wave] = p1; }
    __syncthreads();
    if (tid == 0) {
        out[b * 2 + 0] = r0[0] + r0[1] + r0[2] + r0[3] + bias[0];
        out[b * 2 + 1] = r1[0] + r1[1] + r1[2] + r1[3] + bias[1];
    }
}

extern "C" void kernel_launch(void* const* d_in, const int* in_sizes, int n_in,
                              void* d_out, int out_size, void* d_ws, size_t ws_size,
                              hipStream_t stream)
{
    const int* word_ids = (const int*)d_in[0];
    const int* adjm     = (const int*)d_in[1];
    const int* etyp     = (const int*)d_in[2];
    const float* wemb   = (const float*)d_in[3];
    const float* eemb   = (const float*)d_in[4];
    const float* Wq     = (const float*)d_in[5];
    const float* bq     = (const float*)d_in[6];
    const float* Wk     = (const float*)d_in[7];
    const float* bk     = (const float*)d_in[8];
    const float* Wv     = (const float*)d_in[9];
    const float* bv     = (const float*)d_in[10];
    const float* Wo     = (const float*)d_in[11];
    const float* bo     = (const float*)d_in[12];
    const float* ln1g   = (const float*)d_in[13];
    const float* ln1b   = (const float*)d_in[14];
    const float* W1     = (const float*)d_in[15];
    const float* b1     = (const float*)d_in[16];
    const float* W2     = (const float*)d_in[17];
    const float* b2     = (const float*)d_in[18];
    const float* ln2g   = (const float*)d_in[19];
    const float* ln2b   = (const float*)d_in[20];
    const float* clsW   = (const float*)d_in[21];
    const float* clsb   = (const float*)d_in[22];
    float* outp = (float*)d_out;

    char* ws = (char*)d_ws;
    size_t off = 0;
    auto alloc = [&](size_t bytes) -> char* {
        char* p = ws + off;
        off += (bytes + 255) & ~(size_t)255;
        return p;
    };
    const size_t DxD = (size_t)DD * DD;
    const size_t DxF = (size_t)DD * FF;
    const size_t TOK = (size_t)BB * LL;
    const size_t LSTR = (size_t)QKVS * DD + DxD + 2 * DxF;  // cached bf16 elems / layer = 7,077,888

    // ---- proven-safe base (61.34 MB, same as round-2's passing layout) ----
    float*    hf  = (float*)alloc(TOK * DD * 4);        // 12.58 MB
    ushort_t* hb  = (ushort_t*)alloc(TOK * DD * 2);     //  6.29 MB
    ushort_t* qkv = (ushort_t*)alloc(TOK * QKVS * 2);   // 18.87 MB  (q|k|v fused)
    ushort_t* ao  = (ushort_t*)alloc(TOK * DD * 2);     //  6.29 MB
    float*    pjf = (float*)alloc(TOK * DD * 4);        // 12.58 MB  (partial 0)
    ushort_t* tw  = (ushort_t*)alloc(DxF * 2);          //  4.72 MB  JIT transpose slot
    ushort_t* ff1 = qkv;  // aliases qkv+ao span (exactly 25.17 MB), dead by FFN time
    // ---- tiers by ws_size ----
    size_t tier1 = off + TOK * DD * 4;                  // +1 partial
    size_t tier2 = tier1 + 2 * TOK * DD * 4;            // +3 partials total
    size_t tier3 = tier2 + NLL * LSTR * 2;              // + full transposed-weight cache
    int S_o = 1, S_f = 1;
    ushort_t* cache = nullptr;
    if (ws_size >= tier1) { (void)alloc(TOK * DD * 4); S_o = 2; S_f = 2; }
    if (ws_size >= tier2) { (void)alloc(2 * TOK * DD * 4); S_f = 4; }
    if (ws_size >= tier3) { cache = (ushort_t*)alloc(NLL * LSTR * 2); }
    (void)in_sizes; (void)n_in; (void)out_size;

    dim3 tb(32, 8, 1);
    if (cache) {  // pre-transpose ALL weights, batched over layers (grid.z = 4)
        transpose_f2b<<<dim3(24, 24, NLL), tb, 0, stream>>>(Wq, cache,                 DD, DD, DxD, LSTR);
        transpose_f2b<<<dim3(24, 24, NLL), tb, 0, stream>>>(Wk, cache + DD * DD,       DD, DD, DxD, LSTR);
        transpose_f2b<<<dim3(24, 24, NLL), tb, 0, stream>>>(Wv, cache + 2 * DD * DD,   DD, DD, DxD, LSTR);
        transpose_f2b<<<dim3(24, 24, NLL), tb, 0, stream>>>(Wo, cache + 3 * DD * DD,   DD, DD, DxD, LSTR);
        transpose_f2b<<<dim3(96, 24, NLL), tb, 0, stream>>>(W1, cache + 4 * DD * DD,   DD, FF, DxF, LSTR);
        transpose_f2b<<<dim3(24, 96, NLL), tb, 0, stream>>>(W2, cache + 4 * DD * DD + DxF, FF, DD, DxF, LSTR);
    }

    embed_kernel<<<(int)(TOK * DD / 256), 256, 0, stream>>>(word_ids, wemb, hf, hb);

    const int M = (int)TOK; // 4096
    for (int l = 0; l < NLL; ++l) {
        const ushort_t *BtQKV, *BtO, *BtW1, *BtW2;
        if (cache) {
            const ushort_t* base = cache + (size_t)l * LSTR;
            BtQKV = base; BtO = base + 3 * DD * DD;
            BtW1 = base + 4 * DD * DD; BtW2 = base + 4 * DD * DD + DxF;
        } else {
            BtQKV = tw; BtO = tw; BtW1 = tw; BtW2 = tw;
        }
        // fused QKV bias into (dead-at-this-point) pjf
        fuse_bias_kernel<<<9, 256, 0, stream>>>(bq, bk, bv, l, pjf);
        if (!cache) {
            transpose_f2b<<<dim3(24, 24), tb, 0, stream>>>(Wq + (size_t)l * DxD, tw,               DD, DD, 0, 0);
            transpose_f2b<<<dim3(24, 24), tb, 0, stream>>>(Wk + (size_t)l * DxD, tw + DD * DD,     DD, DD, 0, 0);
            transpose_f2b<<<dim3(24, 24), tb, 0, stream>>>(Wv + (size_t)l * DxD, tw + 2 * DD * DD, DD, DD, 0, 0);
        }
        gemm_bf16<<<dim3(QKVS / 128, M / 128, 1), 256, 0, stream>>>(
            hb, BtQKV, pjf, qkv, nullptr, M, QKVS, DD, DD, 0);
        attn_kernel<<<BB * HH * 16, 256, 0, stream>>>(qkv, adjm, etyp, eemb, ao);
        if (!cache)
            transpose_f2b<<<dim3(24, 24), tb, 0, stream>>>(Wo + (size_t)l * DxD, tw, DD, DD, 0, 0);
        gemm_bf16<<<dim3(DD / 128, M / 128, S_o), 256, 0, stream>>>(
            ao, BtO, bo + l * DD, nullptr, pjf, M, DD, DD, DD / S_o, 0);
        ln_kernel<<<M, 256, 0, stream>>>(hf, hb, pjf, S_o, ln1g + l * DD, ln1b + l * DD);
        if (!cache)
            transpose_f2b<<<dim3(96, 24), tb, 0, stream>>>(W1 + (size_t)l * DxF, tw, DD, FF, 0, 0);
        gemm_bf16<<<dim3(FF / 128, M / 128, 1), 256, 0, stream>>>(
            hb, BtW1, b1 + l * FF, ff1, nullptr, M, FF, DD, DD, 1);
        if (!cache)
            transpose_f2b<<<dim3(24, 96), tb, 0, stream>>>(W2 + (size_t)l * DxF, tw, FF, DD, 0, 0);
        gemm_bf16<<<dim3(DD / 128, M / 128, S_f), 256, 0, stream>>>(
            ff1, BtW2, b2 + l * DD, nullptr, pjf, M, DD, FF, FF / S_f, 0);
        ln_kernel<<<M, 256, 0, stream>>>(hf, hb, pjf, S_f, ln2g + l * DD, ln2b + l * DD);
    }
    cls_kernel<<<BB, 256, 0, stream>>>(hf, clsW, clsb, outp);
}

// Round 3
// 1151.387 us; speedup vs baseline: 1.0538x; 1.0538x over previous
//
#include <hip/hip_runtime.h>
#include <hip/hip_bf16.h>

// Model dims (fixed by the reference)
#define BB 16
#define LL 256
#define DD 768
#define HH 12
#define HDD 64
#define NLL 4
#define FF 3072
#define EE 50
#define QKVS 2304            // fused q|k|v row stride
#define TOKD ((size_t)BB * LL * DD)   // 3,145,728

typedef unsigned short ushort_t;
typedef __bf16 bf16x8 __attribute__((ext_vector_type(8)));
typedef float f32x4 __attribute__((ext_vector_type(4)));

__device__ __forceinline__ float b2f(ushort_t u) {
    union { unsigned int i; float f; } x; x.i = ((unsigned int)u) << 16; return x.f;
}
__device__ __forceinline__ ushort_t f2b(float f) {
    unsigned int u = __builtin_bit_cast(unsigned int, f);
    unsigned int r = u + 0x7fffu + ((u >> 16) & 1u);   // RNE
    return (ushort_t)(r >> 16);
}

__device__ __forceinline__ void gl2lds16(const void* g, void* l) {
    __builtin_amdgcn_global_load_lds(
        (const __attribute__((address_space(1))) unsigned int*)g,
        (__attribute__((address_space(3))) unsigned int*)l,
        16, 0, 0);
}

// ---------------- fused transpose + fp32->bf16: out[C,R] = bf16(in[R,C]^T), batched over z ----------------
__global__ __launch_bounds__(256) void transpose_f2b(
    const float* __restrict__ in, ushort_t* __restrict__ out, int R, int C,
    long inZ, long outZ)
{
    __shared__ ushort_t tile[32][33];
    in  += (long)blockIdx.z * inZ;
    out += (long)blockIdx.z * outZ;
    int c0 = blockIdx.x * 32, r0 = blockIdx.y * 32;
    int tx = threadIdx.x, ty = threadIdx.y; // (32,8)
#pragma unroll
    for (int i = 0; i < 32; i += 8)
        tile[ty + i][tx] = f2b(in[(long)(r0 + ty + i) * C + c0 + tx]);
    __syncthreads();
#pragma unroll
    for (int i = 0; i < 32; i += 8)
        out[(long)(c0 + ty + i) * R + r0 + tx] = tile[tx][ty + i];
}

// ---------------- concat bq|bk|bv for layer l into float[2304] ----------------
__global__ __launch_bounds__(256) void fuse_bias_kernel(
    const float* __restrict__ bq, const float* __restrict__ bk,
    const float* __restrict__ bv, int l, float* __restrict__ out)
{
    int n = blockIdx.x * 256 + threadIdx.x;
    if (n >= QKVS) return;
    float v = (n < DD) ? bq[l * DD + n]
            : (n < 2 * DD) ? bk[l * DD + n - DD]
            : bv[l * DD + n - 2 * DD];
    out[n] = v;
}

// ---------------- embedding + sinusoidal pos ----------------
__global__ __launch_bounds__(256) void embed_kernel(
    const int* __restrict__ wids, const float* __restrict__ wemb,
    float* __restrict__ hf, ushort_t* __restrict__ hb)
{
    long idx = (long)blockIdx.x * 256 + threadIdx.x; // < 4096*768
    int d = (int)(idx % DD);
    int t = (int)(idx / DD);
    int lpos = t & (LL - 1);
    int wid = wids[t];
    float freq = expf(-9.210340371976184f * (float)(d & ~1) * (1.f / (float)DD));
    float ang = (float)lpos * freq;
    float pe = (d & 1) ? cosf(ang) : sinf(ang);
    float hv = wemb[(long)wid * DD + d] + pe;
    hf[idx] = hv;
    hb[idx] = f2b(hv);
}

// ---------------- bf16 MFMA GEMM with optional split-K over blockIdx.z ----------------
// C[M,N] = A[M,K] @ Bt[N,K]^T (+ bias on z==0). Slice z covers k in [z*Ksl, (z+1)*Ksl).
// fp32 output goes to outf + z*M*N (partials summed later). 128x128 tile, BK=32.
// T4 pipeline: 3 LDS buffers, depth-2 prefetch, counted s_waitcnt vmcnt(4).
__global__ __launch_bounds__(256) void gemm_bf16(
    const ushort_t* __restrict__ A, const ushort_t* __restrict__ Bt,
    const float* __restrict__ bias,
    ushort_t* __restrict__ outb, float* __restrict__ outf,
    int M, int N, int K, int Ksl, int relu)
{
    __shared__ __align__(16) ushort_t As[3][128 * 32];
    __shared__ __align__(16) ushort_t Bs[3][128 * 32];
    const int tid = threadIdx.x;
    const int wave = tid >> 6, lane = tid & 63;
    const int quad = lane >> 4, l16 = lane & 15;
    const int m0 = blockIdx.y * 128, n0 = blockIdx.x * 128;
    const int z = blockIdx.z;
    const int kbase = z * Ksl;
    const int wm = (wave >> 1) * 64, wn = (wave & 1) * 64;
    const ushort_t* Ab = A + (long)m0 * K;
    const ushort_t* Bb = Bt + (long)n0 * K;

    const int srow = tid >> 2, skc = (tid & 3) * 8;

    f32x4 acc[4][4];
#pragma unroll
    for (int mi = 0; mi < 4; ++mi)
#pragma unroll
        for (int ni = 0; ni < 4; ++ni) acc[mi][ni] = (f32x4){0.f, 0.f, 0.f, 0.f};

    const int nk = Ksl >> 5;

    // 4 VMEM instructions per stage per wave (2 A + 2 B)
    auto stage = [&](int kt, ushort_t* Ad, ushort_t* Bd) {
        const int k0 = kbase + (kt << 5);
        const ushort_t* ga = &Ab[(long)srow * K + k0 + skc];
        const ushort_t* gb = &Bb[(long)srow * K + k0 + skc];
        char* la = (char*)Ad + wave * 1024;
        char* lb = (char*)Bd + wave * 1024;
        gl2lds16(ga, la);
        gl2lds16(gb, lb);
        gl2lds16(ga + (long)64 * K, la + 4096);
        gl2lds16(gb + (long)64 * K, lb + 4096);
    };

    ushort_t *A0 = As[0], *A1 = As[1], *A2 = As[2];
    ushort_t *B0 = Bs[0], *B1 = Bs[1], *B2 = Bs[2];

    stage(0, A0, B0);
    stage(1, A1, B1);

    for (int kt = 0; kt < nk; ++kt) {
        if (kt + 1 < nk) {
            asm volatile("s_waitcnt vmcnt(4)" ::: "memory");
        } else {
            asm volatile("s_waitcnt vmcnt(0)" ::: "memory");
        }
        __builtin_amdgcn_s_barrier();
        __builtin_amdgcn_sched_barrier(0);
        if (kt + 2 < nk) stage(kt + 2, A2, B2);
        bf16x8 af[4], bfr[4];
#pragma unroll
        for (int t = 0; t < 4; ++t)
            af[t] = *(const bf16x8*)&A0[(wm + t * 16 + l16) * 32 + quad * 8];
#pragma unroll
        for (int t = 0; t < 4; ++t)
            bfr[t] = *(const bf16x8*)&B0[(wn + t * 16 + l16) * 32 + quad * 8];
#pragma unroll
        for (int mi = 0; mi < 4; ++mi)
#pragma unroll
            for (int ni = 0; ni < 4; ++ni)
                acc[mi][ni] = __builtin_amdgcn_mfma_f32_16x16x32_bf16(
                    af[mi], bfr[ni], acc[mi][ni], 0, 0, 0);
        ushort_t* ta = A0; A0 = A1; A1 = A2; A2 = ta;
        ushort_t* tb = B0; B0 = B1; B1 = B2; B2 = tb;
    }

    float* outfz = outf ? outf + (size_t)z * M * N : nullptr;
#pragma unroll
    for (int ni = 0; ni < 4; ++ni) {
        int col = n0 + wn + ni * 16 + l16;
        float bv = (bias && z == 0) ? bias[col] : 0.f;
#pragma unroll
        for (int mi = 0; mi < 4; ++mi) {
#pragma unroll
            for (int r = 0; r < 4; ++r) {
                int row = m0 + wm + mi * 16 + quad * 4 + r;
                float vv = acc[mi][ni][r] + bv;
                if (relu) vv = fmaxf(vv, 0.f);
                if (outb) outb[(long)row * N + col] = f2b(vv);
                if (outfz) outfz[(long)row * N + col] = vv;
            }
        }
    }
}

// ---------------- MFMA attention (fused qkv input, stride 2304) ----------------
// Restructured vs prev round:
//  * V + adj/etyp loaded to REGISTERS at kernel top (T14 async-stage; one merged
//    latency exposure at the first barrier instead of two serial ones).
//  * VT build deferred until after softmax, aliasing the then-dead S/Pe region:
//    LDS 64.4K -> 44.6K => 3 blocks/CU instead of 2.
//  * VT writes/reads XOR-swizzled (col ^= ((row>>3)&7)<<3): kills the 8-way
//    bank conflict of the d0-strided scatter (row stride 132 dwords = 4 mod 32;
//    8 rows -> same bank). 8-elem read runs stay contiguous & 16B-aligned.
//  * XCD-chunked block swizzle: the 16 blocks sharing one (b,h) K/V panel land
//    on one XCD's L2 (3072 % 8 == 0 -> bijective).
#define QS_STR 72
#define VT_STR 264
#define P_STR  264
#define S_STR  257
#define PE_STR 53

#define SM_S    0        // f32 S 16x257 = 16448 B   (phases 1-3)
#define SM_PE   16448    // f32 Pe 16x53 = 3392 B    (phases 1-3)
#define SM_VT   0        // bf16 VT 64x264 = 33792 B (phase 4, aliases S/Pe)
#define SM_P    33792    // bf16 P 16x264 = 8448 B
#define SM_U    42240    // Qs 2304 / red 2176
#define SM_INV  44544    // 16 f32
#define SM_SZ   44608

__global__ __launch_bounds__(256) void attn_kernel(
    const ushort_t* __restrict__ qkv,
    const int* __restrict__ adjm, const int* __restrict__ etyp,
    const float* __restrict__ eemb, ushort_t* __restrict__ out)
{
    __shared__ __align__(16) char smem[SM_SZ];
    float*    S  = (float*)(smem + SM_S);
    float*    Pe = (float*)(smem + SM_PE);
    ushort_t* VT = (ushort_t*)(smem + SM_VT);
    ushort_t* P  = (ushort_t*)(smem + SM_P);
    char*     U  = smem + SM_U;
    float* invrow = (float*)(smem + SM_INV);
    ushort_t* Qs = (ushort_t*)U;
    float*    red = (float*)U;

    // XCD-chunked swizzle: hw ids round-robin over 8 XCDs; give each XCD a
    // contiguous work chunk so same-(b,h) blocks share one L2.
    const int wgid = blockIdx.x;
    const int blk = (wgid & 7) * ((BB * HH * 16) / 8) + (wgid >> 3);
    const int qt = blk & 15;
    const int h  = (blk >> 4) % HH;
    const int b  = blk / (16 * HH);
    const int i0 = qt * 16;
    const int tid = threadIdx.x;
    const int wave = tid >> 6, lane = tid & 63;
    const int quad = lane >> 4, l16 = lane & 15;

    // ---- early issue: V tile into registers (consumed at VT build) ----
    const int vd0 = (tid & 7) * 8;   // head-dim start (fixed per thread)
    const int vj0 = tid >> 3;        // position base, +32 per chunk
    int4 vreg[8];
#pragma unroll
    for (int i = 0; i < 8; ++i)
        vreg[i] = *(const int4*)&qkv[((long)(b * LL + vj0 + 32 * i)) * QKVS + 2 * DD + h * HDD + vd0];

    // ---- early issue: adjacency + edge-type rows (consumed in softmax) ----
    const int arow = tid & 15, aseg = tid >> 4;
    int etv[16], adv[16];
    {
        const int* etp = etyp + ((long)(b * LL + i0 + arow)) * LL + aseg * 16;
        const int* adp = adjm + ((long)(b * LL + i0 + arow)) * LL + aseg * 16;
#pragma unroll
        for (int t = 0; t < 4; ++t) {
            *(int4*)&etv[t * 4] = *(const int4*)&etp[t * 4];
            *(int4*)&adv[t * 4] = *(const int4*)&adp[t * 4];
        }
    }

    // ---- stage Qs (16x64) ----
    if (tid < 128) {
        int row = tid >> 3, d0 = (tid & 7) * 8;
        *(int4*)&Qs[row * QS_STR + d0] =
            *(const int4*)&qkv[((long)(b * LL + i0 + row)) * QKVS + h * HDD + d0];
    }
    __syncthreads();

    // ---- phase 1: Pe = Q @ E^T ----
    {
        int e = wave * 16 + l16;
        f32x4 acc = (f32x4){0.f, 0.f, 0.f, 0.f};
#pragma unroll
        for (int kk = 0; kk < 2; ++kk) {
            bf16x8 af = *(const bf16x8*)&Qs[l16 * QS_STR + kk * 32 + quad * 8];
            bf16x8 bf = (bf16x8){0, 0, 0, 0, 0, 0, 0, 0};
            if (e < EE) {
                const float* ep = &eemb[(long)e * HDD + kk * 32 + quad * 8];
#pragma unroll
                for (int u = 0; u < 8; ++u) bf[u] = (__bf16)ep[u];
            }
            acc = __builtin_amdgcn_mfma_f32_16x16x32_bf16(af, bf, acc, 0, 0, 0);
        }
        if (e < EE) {
#pragma unroll
            for (int r = 0; r < 4; ++r) Pe[(quad * 4 + r) * PE_STR + e] = acc[r];
        }
    }

    // ---- phase 2: S = Q @ K^T (K B-frags straight from global, L2-hot) ----
#pragma unroll
    for (int jt = 0; jt < 4; ++jt) {
        int jtile = wave * 4 + jt;
        int j = jtile * 16 + l16;
        f32x4 acc = (f32x4){0.f, 0.f, 0.f, 0.f};
#pragma unroll
        for (int kk = 0; kk < 2; ++kk) {
            bf16x8 af = *(const bf16x8*)&Qs[l16 * QS_STR + kk * 32 + quad * 8];
            bf16x8 bf = *(const bf16x8*)&qkv[((long)(b * LL + j)) * QKVS + DD + h * HDD + kk * 32 + quad * 8];
            acc = __builtin_amdgcn_mfma_f32_16x16x32_bf16(af, bf, acc, 0, 0, 0);
        }
#pragma unroll
        for (int r = 0; r < 4; ++r)
            S[(quad * 4 + r) * S_STR + jtile * 16 + l16] = acc[r];
    }
    __syncthreads();

    // ---- phase 3: masked softmax with edge gather (adj/etyp already in regs) ----
    {
        const int row = arow, seg = aseg;
        float vals[16];
        float pmax = -1e30f;
#pragma unroll
        for (int c = 0; c < 16; ++c) {
            float s = S[row * S_STR + seg * 16 + c];
            float pe = Pe[row * PE_STR + etv[c]];
            float vv = adv[c] ? (s + pe) * 0.125f : -1e30f;
            vals[c] = vv;
            pmax = fmaxf(pmax, vv);
        }
        red[row * 17 + seg] = pmax;
        __syncthreads();
        // S and Pe are DEAD from here on (all reads happened above).
        float m = -1e30f;
#pragma unroll
        for (int g = 0; g < 16; ++g) m = fmaxf(m, red[row * 17 + g]);
        float sum = 0.f;
#pragma unroll
        for (int c = 0; c < 16; ++c) {
            float p = __expf(vals[c] - m);
            ushort_t pb = f2b(p);
            sum += b2f(pb);
            P[row * P_STR + seg * 16 + c] = pb;
        }
        red[272 + row * 17 + seg] = sum;
        __syncthreads();

        // ---- VT build from registers into the dead S/Pe region, XOR-swizzled.
        // write: VT[row][ j ^ ((row>>3)<<3) ], row = vd0+u  => (row>>3) = tid&7.
        // Banks: 8 d0-groups now land on 8 distinct 4-bank sets -> conflict-free.
        {
            const int vswz = (tid & 7) << 3;
#pragma unroll
            for (int i = 0; i < 8; ++i) {
                const int jc = (vj0 + 32 * i) ^ vswz;
                const ushort_t* vv = (const ushort_t*)&vreg[i];
#pragma unroll
                for (int u = 0; u < 8; ++u)
                    VT[(vd0 + u) * VT_STR + jc] = vv[u];
            }
        }
        if (tid < 16) {
            float tot = 0.f;
#pragma unroll
            for (int g = 0; g < 16; ++g) tot += red[272 + tid * 17 + g];
            invrow[tid] = 1.f / tot;
        }
        __syncthreads();
    }

    // ---- phase 4: O = P @ V (VT reads use the same XOR swizzle) ----
    {
        const int d = wave * 16 + l16;
        const int rswz = ((d >> 3) & 7) << 3;
        f32x4 acc = (f32x4){0.f, 0.f, 0.f, 0.f};
#pragma unroll
        for (int kt = 0; kt < 8; ++kt) {
            bf16x8 af = *(const bf16x8*)&P[l16 * P_STR + kt * 32 + quad * 8];
            bf16x8 bf = *(const bf16x8*)&VT[d * VT_STR + ((kt * 32 + quad * 8) ^ rswz)];
            acc = __builtin_amdgcn_mfma_f32_16x16x32_bf16(af, bf, acc, 0, 0, 0);
        }
#pragma unroll
        for (int r = 0; r < 4; ++r) {
            int row = quad * 4 + r;
            float ov = acc[r] * invrow[row];
            out[((long)(b * LL + i0 + row)) * DD + h * HDD + d] = f2b(ov);
        }
    }
}

// ---------------- residual + layernorm; sums nparts split-K partials ----------------
__global__ __launch_bounds__(256) void ln_kernel(
    float* __restrict__ hf, ushort_t* __restrict__ hb,
    const float* __restrict__ proj, int nparts,
    const float* __restrict__ g, const float* __restrict__ be)
{
    const int r = blockIdx.x, tid = threadIdx.x;
    const long rb = (long)r * DD;
    float x[3];
#pragma unroll
    for (int i = 0; i < 3; ++i) {
        int d = tid + i * 256;
        float t = hf[rb + d];
        for (int p = 0; p < nparts; ++p) t += proj[(size_t)p * TOKD + rb + d];
        x[i] = t;
    }
    float s = x[0] + x[1] + x[2];
    float s2 = x[0] * x[0] + x[1] * x[1] + x[2] * x[2];
#pragma unroll
    for (int o = 1; o < 64; o <<= 1) { s += __shfl_xor(s, o); s2 += __shfl_xor(s2, o); }
    __shared__ float rs[4], rq[4];
    int wave = tid >> 6;
    if ((tid & 63) == 0) { rs[wave] = s; rq[wave] = s2; }
    __syncthreads();
    float S  = rs[0] + rs[1] + rs[2] + rs[3];
    float S2 = rq[0] + rq[1] + rq[2] + rq[3];
    float mean = S * (1.f / (float)DD);
    float var  = S2 * (1.f / (float)DD) - mean * mean;
    float rstd = rsqrtf(var + 1e-5f);
#pragma unroll
    for (int i = 0; i < 3; ++i) {
        int d = tid + i * 256;
        float y = (x[i] - mean) * rstd * g[d] + be[d];
        hf[rb + d] = y;
        hb[rb + d] = f2b(y);
    }
}

// ---------------- classifier head ----------------
__global__ __launch_bounds__(256) void cls_kernel(
    const float* __restrict__ hf, const float* __restrict__ W,
    const float* __restrict__ bias, float* __restrict__ out)
{
    int b = blockIdx.x, tid = threadIdx.x;
    const float* hr = hf + (long)b * LL * DD;
    float p0 = 0.f, p1 = 0.f;
    for (int d = tid; d < DD; d += 256) {
        float hv = hr[d];
        p0 = fmaf(hv, W[d * 2 + 0], p0);
        p1 = fmaf(hv, W[d * 2 + 1], p1);
    }
#pragma unroll
    for (int o = 1; o < 64; o <<= 1) { p0 += __shfl_xor(p0, o); p1 += __shfl_xor(p1, o); }
    __shared__ float r0[4], r1[4];
    int wave = tid >> 6;
    if ((tid & 63) == 0) { r0[wave] = p0; r1[wave] = p1; }
    __syncthreads();
    if (tid == 0) {
        out[b * 2 + 0] = r0[0] + r0[1] + r0[2] + r0[3] + bias[0];
        out[b * 2 + 1] = r1[0] + r1[1] + r1[2] + r1[3] + bias[1];
    }
}

extern "C" void kernel_launch(void* const* d_in, const int* in_sizes, int n_in,
                              void* d_out, int out_size, void* d_ws, size_t ws_size,
                              hipStream_t stream)
{
    const int* word_ids = (const int*)d_in[0];
    const int* adjm     = (const int*)d_in[1];
    const int* etyp     = (const int*)d_in[2];
    const float* wemb   = (const float*)d_in[3];
    const float* eemb   = (const float*)d_in[4];
    const float* Wq     = (const float*)d_in[5];
    const float* bq     = (const float*)d_in[6];
    const float* Wk     = (const float*)d_in[7];
    const float* bk     = (const float*)d_in[8];
    const float* Wv     = (const float*)d_in[9];
    const float* bv     = (const float*)d_in[10];
    const float* Wo     = (const float*)d_in[11];
    const float* bo     = (const float*)d_in[12];
    const float* ln1g   = (const float*)d_in[13];
    const float* ln1b   = (const float*)d_in[14];
    const float* W1     = (const float*)d_in[15];
    const float* b1     = (const float*)d_in[16];
    const float* W2     = (const float*)d_in[17];
    const float* b2     = (const float*)d_in[18];
    const float* ln2g   = (const float*)d_in[19];
    const float* ln2b   = (const float*)d_in[20];
    const float* clsW   = (const float*)d_in[21];
    const float* clsb   = (const float*)d_in[22];
    float* outp = (float*)d_out;

    char* ws = (char*)d_ws;
    size_t off = 0;
    auto alloc = [&](size_t bytes) -> char* {
        char* p = ws + off;
        off += (bytes + 255) & ~(size_t)255;
        return p;
    };
    const size_t DxD = (size_t)DD * DD;
    const size_t DxF = (size_t)DD * FF;
    const size_t TOK = (size_t)BB * LL;
    const size_t LSTR = (size_t)QKVS * DD + DxD + 2 * DxF;  // cached bf16 elems / layer = 7,077,888

    // ---- proven-safe base (61.34 MB, same as round-2's passing layout) ----
    float*    hf  = (float*)alloc(TOK * DD * 4);        // 12.58 MB
    ushort_t* hb  = (ushort_t*)alloc(TOK * DD * 2);     //  6.29 MB
    ushort_t* qkv = (ushort_t*)alloc(TOK * QKVS * 2);   // 18.87 MB  (q|k|v fused)
    ushort_t* ao  = (ushort_t*)alloc(TOK * DD * 2);     //  6.29 MB
    float*    pjf = (float*)alloc(TOK * DD * 4);        // 12.58 MB  (partial 0)
    ushort_t* tw  = (ushort_t*)alloc(DxF * 2);          //  4.72 MB  JIT transpose slot
    ushort_t* ff1 = qkv;  // aliases qkv+ao span (exactly 25.17 MB), dead by FFN time
    // ---- tiers by ws_size ----
    size_t tier1 = off + TOK * DD * 4;                  // +1 partial
    size_t tier2 = tier1 + 2 * TOK * DD * 4;            // +3 partials total
    size_t tier3 = tier2 + NLL * LSTR * 2;              // + full transposed-weight cache
    int S_o = 1, S_f = 1;
    ushort_t* cache = nullptr;
    if (ws_size >= tier1) { (void)alloc(TOK * DD * 4); S_o = 2; S_f = 2; }
    if (ws_size >= tier2) { (void)alloc(2 * TOK * DD * 4); S_f = 4; }
    if (ws_size >= tier3) { cache = (ushort_t*)alloc(NLL * LSTR * 2); }
    (void)in_sizes; (void)n_in; (void)out_size;

    dim3 tb(32, 8, 1);
    if (cache) {  // pre-transpose ALL weights, batched over layers (grid.z = 4)
        transpose_f2b<<<dim3(24, 24, NLL), tb, 0, stream>>>(Wq, cache,                 DD, DD, DxD, LSTR);
        transpose_f2b<<<dim3(24, 24, NLL), tb, 0, stream>>>(Wk, cache + DD * DD,       DD, DD, DxD, LSTR);
        transpose_f2b<<<dim3(24, 24, NLL), tb, 0, stream>>>(Wv, cache + 2 * DD * DD,   DD, DD, DxD, LSTR);
        transpose_f2b<<<dim3(24, 24, NLL), tb, 0, stream>>>(Wo, cache + 3 * DD * DD,   DD, DD, DxD, LSTR);
        transpose_f2b<<<dim3(96, 24, NLL), tb, 0, stream>>>(W1, cache + 4 * DD * DD,   DD, FF, DxF, LSTR);
        transpose_f2b<<<dim3(24, 96, NLL), tb, 0, stream>>>(W2, cache + 4 * DD * DD + DxF, FF, DD, DxF, LSTR);
    }

    embed_kernel<<<(int)(TOK * DD / 256), 256, 0, stream>>>(word_ids, wemb, hf, hb);

    const int M = (int)TOK; // 4096
    for (int l = 0; l < NLL; ++l) {
        const ushort_t *BtQKV, *BtO, *BtW1, *BtW2;
        if (cache) {
            const ushort_t* base = cache + (size_t)l * LSTR;
            BtQKV = base; BtO = base + 3 * DD * DD;
            BtW1 = base + 4 * DD * DD; BtW2 = base + 4 * DD * DD + DxF;
        } else {
            BtQKV = tw; BtO = tw; BtW1 = tw; BtW2 = tw;
        }
        // fused QKV bias into (dead-at-this-point) pjf
        fuse_bias_kernel<<<9, 256, 0, stream>>>(bq, bk, bv, l, pjf);
        if (!cache) {
            transpose_f2b<<<dim3(24, 24), tb, 0, stream>>>(Wq + (size_t)l * DxD, tw,               DD, DD, 0, 0);
            transpose_f2b<<<dim3(24, 24), tb, 0, stream>>>(Wk + (size_t)l * DxD, tw + DD * DD,     DD, DD, 0, 0);
            transpose_f2b<<<dim3(24, 24), tb, 0, stream>>>(Wv + (size_t)l * DxD, tw + 2 * DD * DD, DD, DD, 0, 0);
        }
        gemm_bf16<<<dim3(QKVS / 128, M / 128, 1), 256, 0, stream>>>(
            hb, BtQKV, pjf, qkv, nullptr, M, QKVS, DD, DD, 0);
        attn_kernel<<<BB * HH * 16, 256, 0, stream>>>(qkv, adjm, etyp, eemb, ao);
        if (!cache)
            transpose_f2b<<<dim3(24, 24), tb, 0, stream>>>(Wo + (size_t)l * DxD, tw, DD, DD, 0, 0);
        gemm_bf16<<<dim3(DD / 128, M / 128, S_o), 256, 0, stream>>>(
            ao, BtO, bo + l * DD, nullptr, pjf, M, DD, DD, DD / S_o, 0);
        ln_kernel<<<M, 256, 0, stream>>>(hf, hb, pjf, S_o, ln1g + l * DD, ln1b + l * DD);
        if (!cache)
            transpose_f2b<<<dim3(96, 24), tb, 0, stream>>>(W1 + (size_t)l * DxF, tw, DD, FF, 0, 0);
        gemm_bf16<<<dim3(FF / 128, M / 128, 1), 256, 0, stream>>>(
            hb, BtW1, b1 + l * FF, ff1, nullptr, M, FF, DD, DD, 1);
        if (!cache)
            transpose_f2b<<<dim3(24, 96), tb, 0, stream>>>(W2 + (size_t)l * DxF, tw, FF, DD, 0, 0);
        gemm_bf16<<<dim3(DD / 128, M / 128, S_f), 256, 0, stream>>>(
            ff1, BtW2, b2 + l * DD, nullptr, pjf, M, DD, FF, FF / S_f, 0);
        ln_kernel<<<M, 256, 0, stream>>>(hf, hb, pjf, S_f, ln2g + l * DD, ln2b + l * DD);
    }
    cls_kernel<<<BB, 256, 0, stream>>>(hf, clsW, clsb, outp);
}

// Round 4
// 1129.095 us; speedup vs baseline: 1.0747x; 1.0197x over previous
//
#include <hip/hip_runtime.h>
#include <hip/hip_bf16.h>

// Model dims (fixed by the reference)
#define BB 16
#define LL 256
#define DD 768
#define HH 12
#define HDD 64
#define NLL 4
#define FF 3072
#define EE 50
#define QKVS 2304            // fused q|k|v row stride
#define TOKD ((size_t)BB * LL * DD)   // 3,145,728

typedef unsigned short ushort_t;
typedef __bf16 bf16x8 __attribute__((ext_vector_type(8)));
typedef float f32x4 __attribute__((ext_vector_type(4)));

__device__ __forceinline__ float b2f(ushort_t u) {
    union { unsigned int i; float f; } x; x.i = ((unsigned int)u) << 16; return x.f;
}
__device__ __forceinline__ ushort_t f2b(float f) {
    unsigned int u = __builtin_bit_cast(unsigned int, f);
    unsigned int r = u + 0x7fffu + ((u >> 16) & 1u);   // RNE
    return (ushort_t)(r >> 16);
}

__device__ __forceinline__ void gl2lds16(const void* g, void* l) {
    __builtin_amdgcn_global_load_lds(
        (const __attribute__((address_space(1))) unsigned int*)g,
        (__attribute__((address_space(3))) unsigned int*)l,
        16, 0, 0);
}

// ---------------- fused transpose + fp32->bf16: out[C,R] = bf16(in[R,C]^T), batched over z ----------------
__global__ __launch_bounds__(256) void transpose_f2b(
    const float* __restrict__ in, ushort_t* __restrict__ out, int R, int C,
    long inZ, long outZ)
{
    __shared__ ushort_t tile[32][33];
    in  += (long)blockIdx.z * inZ;
    out += (long)blockIdx.z * outZ;
    int c0 = blockIdx.x * 32, r0 = blockIdx.y * 32;
    int tx = threadIdx.x, ty = threadIdx.y; // (32,8)
#pragma unroll
    for (int i = 0; i < 32; i += 8)
        tile[ty + i][tx] = f2b(in[(long)(r0 + ty + i) * C + c0 + tx]);
    __syncthreads();
#pragma unroll
    for (int i = 0; i < 32; i += 8)
        out[(long)(c0 + ty + i) * R + r0 + tx] = tile[tx][ty + i];
}

// ---------------- concat bq|bk|bv for layer l into float[2304] ----------------
__global__ __launch_bounds__(256) void fuse_bias_kernel(
    const float* __restrict__ bq, const float* __restrict__ bk,
    const float* __restrict__ bv, int l, float* __restrict__ out)
{
    int n = blockIdx.x * 256 + threadIdx.x;
    if (n >= QKVS) return;
    float v = (n < DD) ? bq[l * DD + n]
            : (n < 2 * DD) ? bk[l * DD + n - DD]
            : bv[l * DD + n - 2 * DD];
    out[n] = v;
}

// ---------------- embedding + sinusoidal pos ----------------
__global__ __launch_bounds__(256) void embed_kernel(
    const int* __restrict__ wids, const float* __restrict__ wemb,
    float* __restrict__ hf, ushort_t* __restrict__ hb)
{
    long idx = (long)blockIdx.x * 256 + threadIdx.x; // < 4096*768
    int d = (int)(idx % DD);
    int t = (int)(idx / DD);
    int lpos = t & (LL - 1);
    int wid = wids[t];
    float freq = expf(-9.210340371976184f * (float)(d & ~1) * (1.f / (float)DD));
    float ang = (float)lpos * freq;
    float pe = (d & 1) ? cosf(ang) : sinf(ang);
    float hv = wemb[(long)wid * DD + d] + pe;
    hf[idx] = hv;
    hb[idx] = f2b(hv);
}

// ---------------- bf16 MFMA GEMM with optional split-K over blockIdx.z ----------------
// C[M,N] = A[M,K] @ Bt[N,K]^T (+ bias on z==0). Slice z covers k in [z*Ksl, (z+1)*Ksl).
// fp32 output goes to outf + z*M*N (partials summed later). 128x128 tile, BK=32.
// T4 pipeline: 3 LDS buffers, depth-2 prefetch, counted s_waitcnt vmcnt(4).
// T1: bijective XCD-chunked block swizzle — the gx consecutive blocks sharing one
// A-row panel land on ONE XCD's L2 instead of being round-robined over 8 L2s
// (A panel was fetched up to gx times into non-coherent L2s -> 3.4x HBM over-fetch).
__global__ __launch_bounds__(256) void gemm_bf16(
    const ushort_t* __restrict__ A, const ushort_t* __restrict__ Bt,
    const float* __restrict__ bias,
    ushort_t* __restrict__ outb, float* __restrict__ outf,
    int M, int N, int K, int Ksl, int relu)
{
    __shared__ __align__(16) ushort_t As[3][128 * 32];
    __shared__ __align__(16) ushort_t Bs[3][128 * 32];
    const int tid = threadIdx.x;
    const int wave = tid >> 6, lane = tid & 63;
    const int quad = lane >> 4, l16 = lane & 15;

    // ---- XCD-chunked bijective remap (m204 formula) ----
    const int gx = gridDim.x, gy = gridDim.y;
    int gid = blockIdx.x + gx * (blockIdx.y + gy * blockIdx.z);
    {
        const int T = gx * gy * gridDim.z;
        const int q = T >> 3, r = T & 7;
        const int xcd = gid & 7, lin = gid >> 3;
        gid = (xcd < r ? xcd * (q + 1) : r * (q + 1) + (xcd - r) * q) + lin;
    }
    const int bx = gid % gx;
    const int byz = gid / gx;
    const int by = byz % gy;
    const int bz = byz / gy;

    const int m0 = by * 128, n0 = bx * 128;
    const int z = bz;
    const int kbase = z * Ksl;
    const int wm = (wave >> 1) * 64, wn = (wave & 1) * 64;
    const ushort_t* Ab = A + (long)m0 * K;
    const ushort_t* Bb = Bt + (long)n0 * K;

    const int srow = tid >> 2, skc = (tid & 3) * 8;

    f32x4 acc[4][4];
#pragma unroll
    for (int mi = 0; mi < 4; ++mi)
#pragma unroll
        for (int ni = 0; ni < 4; ++ni) acc[mi][ni] = (f32x4){0.f, 0.f, 0.f, 0.f};

    const int nk = Ksl >> 5;

    // 4 VMEM instructions per stage per wave (2 A + 2 B)
    auto stage = [&](int kt, ushort_t* Ad, ushort_t* Bd) {
        const int k0 = kbase + (kt << 5);
        const ushort_t* ga = &Ab[(long)srow * K + k0 + skc];
        const ushort_t* gb = &Bb[(long)srow * K + k0 + skc];
        char* la = (char*)Ad + wave * 1024;
        char* lb = (char*)Bd + wave * 1024;
        gl2lds16(ga, la);
        gl2lds16(gb, lb);
        gl2lds16(ga + (long)64 * K, la + 4096);
        gl2lds16(gb + (long)64 * K, lb + 4096);
    };

    ushort_t *A0 = As[0], *A1 = As[1], *A2 = As[2];
    ushort_t *B0 = Bs[0], *B1 = Bs[1], *B2 = Bs[2];

    stage(0, A0, B0);
    stage(1, A1, B1);

    for (int kt = 0; kt < nk; ++kt) {
        if (kt + 1 < nk) {
            asm volatile("s_waitcnt vmcnt(4)" ::: "memory");
        } else {
            asm volatile("s_waitcnt vmcnt(0)" ::: "memory");
        }
        __builtin_amdgcn_s_barrier();
        __builtin_amdgcn_sched_barrier(0);
        if (kt + 2 < nk) stage(kt + 2, A2, B2);
        bf16x8 af[4], bfr[4];
#pragma unroll
        for (int t = 0; t < 4; ++t)
            af[t] = *(const bf16x8*)&A0[(wm + t * 16 + l16) * 32 + quad * 8];
#pragma unroll
        for (int t = 0; t < 4; ++t)
            bfr[t] = *(const bf16x8*)&B0[(wn + t * 16 + l16) * 32 + quad * 8];
#pragma unroll
        for (int mi = 0; mi < 4; ++mi)
#pragma unroll
            for (int ni = 0; ni < 4; ++ni)
                acc[mi][ni] = __builtin_amdgcn_mfma_f32_16x16x32_bf16(
                    af[mi], bfr[ni], acc[mi][ni], 0, 0, 0);
        ushort_t* ta = A0; A0 = A1; A1 = A2; A2 = ta;
        ushort_t* tb = B0; B0 = B1; B1 = B2; B2 = tb;
    }

    float* outfz = outf ? outf + (size_t)z * M * N : nullptr;
#pragma unroll
    for (int ni = 0; ni < 4; ++ni) {
        int col = n0 + wn + ni * 16 + l16;
        float bv = (bias && z == 0) ? bias[col] : 0.f;
#pragma unroll
        for (int mi = 0; mi < 4; ++mi) {
#pragma unroll
            for (int r = 0; r < 4; ++r) {
                int row = m0 + wm + mi * 16 + quad * 4 + r;
                float vv = acc[mi][ni][r] + bv;
                if (relu) vv = fmaxf(vv, 0.f);
                if (outb) outb[(long)row * N + col] = f2b(vv);
                if (outfz) outfz[(long)row * N + col] = vv;
            }
        }
    }
}

// ---------------- MFMA attention (fused qkv input, stride 2304) ----------------
#define QS_STR 72
#define VT_STR 264
#define P_STR  264
#define S_STR  257
#define PE_STR 53

#define SM_S    0        // f32 S 16x257 = 16448 B   (phases 1-3)
#define SM_PE   16448    // f32 Pe 16x53 = 3392 B    (phases 1-3)
#define SM_VT   0        // bf16 VT 64x264 = 33792 B (phase 4, aliases S/Pe)
#define SM_P    33792    // bf16 P 16x264 = 8448 B
#define SM_U    42240    // Qs 2304 / red 2176
#define SM_INV  44544    // 16 f32
#define SM_SZ   44608

__global__ __launch_bounds__(256) void attn_kernel(
    const ushort_t* __restrict__ qkv,
    const int* __restrict__ adjm, const int* __restrict__ etyp,
    const float* __restrict__ eemb, ushort_t* __restrict__ out)
{
    __shared__ __align__(16) char smem[SM_SZ];
    float*    S  = (float*)(smem + SM_S);
    float*    Pe = (float*)(smem + SM_PE);
    ushort_t* VT = (ushort_t*)(smem + SM_VT);
    ushort_t* P  = (ushort_t*)(smem + SM_P);
    char*     U  = smem + SM_U;
    float* invrow = (float*)(smem + SM_INV);
    ushort_t* Qs = (ushort_t*)U;
    float*    red = (float*)U;

    // XCD-chunked swizzle: same-(b,h) blocks share one L2.
    const int wgid = blockIdx.x;
    const int blk = (wgid & 7) * ((BB * HH * 16) / 8) + (wgid >> 3);
    const int qt = blk & 15;
    const int h  = (blk >> 4) % HH;
    const int b  = blk / (16 * HH);
    const int i0 = qt * 16;
    const int tid = threadIdx.x;
    const int wave = tid >> 6, lane = tid & 63;
    const int quad = lane >> 4, l16 = lane & 15;

    // ---- early issue: V tile into registers (consumed at VT build) ----
    const int vd0 = (tid & 7) * 8;   // head-dim start (fixed per thread)
    const int vj0 = tid >> 3;        // position base, +32 per chunk
    int4 vreg[8];
#pragma unroll
    for (int i = 0; i < 8; ++i)
        vreg[i] = *(const int4*)&qkv[((long)(b * LL + vj0 + 32 * i)) * QKVS + 2 * DD + h * HDD + vd0];

    // ---- early issue: adjacency + edge-type rows (consumed in softmax) ----
    const int arow = tid & 15, aseg = tid >> 4;
    int etv[16], adv[16];
    {
        const int* etp = etyp + ((long)(b * LL + i0 + arow)) * LL + aseg * 16;
        const int* adp = adjm + ((long)(b * LL + i0 + arow)) * LL + aseg * 16;
#pragma unroll
        for (int t = 0; t < 4; ++t) {
            *(int4*)&etv[t * 4] = *(const int4*)&etp[t * 4];
            *(int4*)&adv[t * 4] = *(const int4*)&adp[t * 4];
        }
    }

    // ---- stage Qs (16x64) ----
    if (tid < 128) {
        int row = tid >> 3, d0 = (tid & 7) * 8;
        *(int4*)&Qs[row * QS_STR + d0] =
            *(const int4*)&qkv[((long)(b * LL + i0 + row)) * QKVS + h * HDD + d0];
    }
    __syncthreads();

    // ---- phase 1: Pe = Q @ E^T ----
    {
        int e = wave * 16 + l16;
        f32x4 acc = (f32x4){0.f, 0.f, 0.f, 0.f};
#pragma unroll
        for (int kk = 0; kk < 2; ++kk) {
            bf16x8 af = *(const bf16x8*)&Qs[l16 * QS_STR + kk * 32 + quad * 8];
            bf16x8 bf = (bf16x8){0, 0, 0, 0, 0, 0, 0, 0};
            if (e < EE) {
                const float* ep = &eemb[(long)e * HDD + kk * 32 + quad * 8];
#pragma unroll
                for (int u = 0; u < 8; ++u) bf[u] = (__bf16)ep[u];
            }
            acc = __builtin_amdgcn_mfma_f32_16x16x32_bf16(af, bf, acc, 0, 0, 0);
        }
        if (e < EE) {
#pragma unroll
            for (int r = 0; r < 4; ++r) Pe[(quad * 4 + r) * PE_STR + e] = acc[r];
        }
    }

    // ---- phase 2: S = Q @ K^T (K B-frags straight from global, L2-hot) ----
#pragma unroll
    for (int jt = 0; jt < 4; ++jt) {
        int jtile = wave * 4 + jt;
        int j = jtile * 16 + l16;
        f32x4 acc = (f32x4){0.f, 0.f, 0.f, 0.f};
#pragma unroll
        for (int kk = 0; kk < 2; ++kk) {
            bf16x8 af = *(const bf16x8*)&Qs[l16 * QS_STR + kk * 32 + quad * 8];
            bf16x8 bf = *(const bf16x8*)&qkv[((long)(b * LL + j)) * QKVS + DD + h * HDD + kk * 32 + quad * 8];
            acc = __builtin_amdgcn_mfma_f32_16x16x32_bf16(af, bf, acc, 0, 0, 0);
        }
#pragma unroll
        for (int r = 0; r < 4; ++r)
            S[(quad * 4 + r) * S_STR + jtile * 16 + l16] = acc[r];
    }
    __syncthreads();

    // ---- phase 3: masked softmax with edge gather (adj/etyp already in regs) ----
    {
        const int row = arow, seg = aseg;
        float vals[16];
        float pmax = -1e30f;
#pragma unroll
        for (int c = 0; c < 16; ++c) {
            float s = S[row * S_STR + seg * 16 + c];
            float pe = Pe[row * PE_STR + etv[c]];
            float vv = adv[c] ? (s + pe) * 0.125f : -1e30f;
            vals[c] = vv;
            pmax = fmaxf(pmax, vv);
        }
        red[row * 17 + seg] = pmax;
        __syncthreads();
        // S and Pe are DEAD from here on (all reads happened above).
        float m = -1e30f;
#pragma unroll
        for (int g = 0; g < 16; ++g) m = fmaxf(m, red[row * 17 + g]);
        float sum = 0.f;
#pragma unroll
        for (int c = 0; c < 16; ++c) {
            float p = __expf(vals[c] - m);
            ushort_t pb = f2b(p);
            sum += b2f(pb);
            P[row * P_STR + seg * 16 + c] = pb;
        }
        red[272 + row * 17 + seg] = sum;
        __syncthreads();

        // ---- VT build from registers into the dead S/Pe region, XOR-swizzled.
        {
            const int vswz = (tid & 7) << 3;
#pragma unroll
            for (int i = 0; i < 8; ++i) {
                const int jc = (vj0 + 32 * i) ^ vswz;
                const ushort_t* vv = (const ushort_t*)&vreg[i];
#pragma unroll
                for (int u = 0; u < 8; ++u)
                    VT[(vd0 + u) * VT_STR + jc] = vv[u];
            }
        }
        if (tid < 16) {
            float tot = 0.f;
#pragma unroll
            for (int g = 0; g < 16; ++g) tot += red[272 + tid * 17 + g];
            invrow[tid] = 1.f / tot;
        }
        __syncthreads();
    }

    // ---- phase 4: O = P @ V (VT reads use the same XOR swizzle) ----
    {
        const int d = wave * 16 + l16;
        const int rswz = ((d >> 3) & 7) << 3;
        f32x4 acc = (f32x4){0.f, 0.f, 0.f, 0.f};
#pragma unroll
        for (int kt = 0; kt < 8; ++kt) {
            bf16x8 af = *(const bf16x8*)&P[l16 * P_STR + kt * 32 + quad * 8];
            bf16x8 bf = *(const bf16x8*)&VT[d * VT_STR + ((kt * 32 + quad * 8) ^ rswz)];
            acc = __builtin_amdgcn_mfma_f32_16x16x32_bf16(af, bf, acc, 0, 0, 0);
        }
#pragma unroll
        for (int r = 0; r < 4; ++r) {
            int row = quad * 4 + r;
            float ov = acc[r] * invrow[row];
            out[((long)(b * LL + i0 + row)) * DD + h * HDD + d] = f2b(ov);
        }
    }
}

// ---------------- residual + layernorm; sums nparts split-K partials ----------------
__global__ __launch_bounds__(256) void ln_kernel(
    float* __restrict__ hf, ushort_t* __restrict__ hb,
    const float* __restrict__ proj, int nparts,
    const float* __restrict__ g, const float* __restrict__ be)
{
    const int r = blockIdx.x, tid = threadIdx.x;
    const long rb = (long)r * DD;
    float x[3];
#pragma unroll
    for (int i = 0; i < 3; ++i) {
        int d = tid + i * 256;
        float t = hf[rb + d];
        for (int p = 0; p < nparts; ++p) t += proj[(size_t)p * TOKD + rb + d];
        x[i] = t;
    }
    float s = x[0] + x[1] + x[2];
    float s2 = x[0] * x[0] + x[1] * x[1] + x[2] * x[2];
#pragma unroll
    for (int o = 1; o < 64; o <<= 1) { s += __shfl_xor(s, o); s2 += __shfl_xor(s2, o); }
    __shared__ float rs[4], rq[4];
    int wave = tid >> 6;
    if ((tid & 63) == 0) { rs[wave] = s; rq[wave] = s2; }
    __syncthreads();
    float S  = rs[0] + rs[1] + rs[2] + rs[3];
    float S2 = rq[0] + rq[1] + rq[2] + rq[3];
    float mean = S * (1.f / (float)DD);
    float var  = S2 * (1.f / (float)DD) - mean * mean;
    float rstd = rsqrtf(var + 1e-5f);
#pragma unroll
    for (int i = 0; i < 3; ++i) {
        int d = tid + i * 256;
        float y = (x[i] - mean) * rstd * g[d] + be[d];
        hf[rb + d] = y;
        hb[rb + d] = f2b(y);
    }
}

// ---------------- classifier head ----------------
__global__ __launch_bounds__(256) void cls_kernel(
    const float* __restrict__ hf, const float* __restrict__ W,
    const float* __restrict__ bias, float* __restrict__ out)
{
    int b = blockIdx.x, tid = threadIdx.x;
    const float* hr = hf + (long)b * LL * DD;
    float p0 = 0.f, p1 = 0.f;
    for (int d = tid; d < DD; d += 256) {
        float hv = hr[d];
        p0 = fmaf(hv, W[d * 2 + 0], p0);
        p1 = fmaf(hv, W[d * 2 + 1], p1);
    }
#pragma unroll
    for (int o = 1; o < 64; o <<= 1) { p0 += __shfl_xor(p0, o); p1 += __shfl_xor(p1, o); }
    __shared__ float r0[4], r1[4];
    int wave = tid >> 6;
    if ((tid & 63) == 0) { r0[wave] = p0; r1[wave] = p1; }
    __syncthreads();
    if (tid == 0) {
        out[b * 2 + 0] = r0[0] + r0[1] + r0[2] + r0[3] + bias[0];
        out[b * 2 + 1] = r1[0] + r1[1] + r1[2] + r1[3] + bias[1];
    }
}

extern "C" void kernel_launch(void* const* d_in, const int* in_sizes, int n_in,
                              void* d_out, int out_size, void* d_ws, size_t ws_size,
                              hipStream_t stream)
{
    const int* word_ids = (const int*)d_in[0];
    const int* adjm     = (const int*)d_in[1];
    const int* etyp     = (const int*)d_in[2];
    const float* wemb   = (const float*)d_in[3];
    const float* eemb   = (const float*)d_in[4];
    const float* Wq     = (const float*)d_in[5];
    const float* bq     = (const float*)d_in[6];
    const float* Wk     = (const float*)d_in[7];
    const float* bk     = (const float*)d_in[8];
    const float* Wv     = (const float*)d_in[9];
    const float* bv     = (const float*)d_in[10];
    const float* Wo     = (const float*)d_in[11];
    const float* bo     = (const float*)d_in[12];
    const float* ln1g   = (const float*)d_in[13];
    const float* ln1b   = (const float*)d_in[14];
    const float* W1     = (const float*)d_in[15];
    const float* b1     = (const float*)d_in[16];
    const float* W2     = (const float*)d_in[17];
    const float* b2     = (const float*)d_in[18];
    const float* ln2g   = (const float*)d_in[19];
    const float* ln2b   = (const float*)d_in[20];
    const float* clsW   = (const float*)d_in[21];
    const float* clsb   = (const float*)d_in[22];
    float* outp = (float*)d_out;

    char* ws = (char*)d_ws;
    size_t off = 0;
    auto alloc = [&](size_t bytes) -> char* {
        char* p = ws + off;
        off += (bytes + 255) & ~(size_t)255;
        return p;
    };
    const size_t DxD = (size_t)DD * DD;
    const size_t DxF = (size_t)DD * FF;
    const size_t TOK = (size_t)BB * LL;
    const size_t LSTR = (size_t)QKVS * DD + DxD + 2 * DxF;  // cached bf16 elems / layer = 7,077,888

    // ---- proven-safe base (61.34 MB, same as round-2's passing layout) ----
    float*    hf  = (float*)alloc(TOK * DD * 4);        // 12.58 MB
    ushort_t* hb  = (ushort_t*)alloc(TOK * DD * 2);     //  6.29 MB
    ushort_t* qkv = (ushort_t*)alloc(TOK * QKVS * 2);   // 18.87 MB  (q|k|v fused)
    ushort_t* ao  = (ushort_t*)alloc(TOK * DD * 2);     //  6.29 MB
    float*    pjf = (float*)alloc(TOK * DD * 4);        // 12.58 MB  (partial 0)
    ushort_t* tw  = (ushort_t*)alloc(DxF * 2);          //  4.72 MB  JIT transpose slot
    ushort_t* ff1 = qkv;  // aliases qkv+ao span (exactly 25.17 MB), dead by FFN time
    // ---- tiers by ws_size ----
    size_t tier1 = off + TOK * DD * 4;                  // +1 partial
    size_t tier2 = tier1 + 2 * TOK * DD * 4;            // +3 partials total
    size_t tier3 = tier2 + NLL * LSTR * 2;              // + full transposed-weight cache
    int S_o = 1, S_f = 1;
    ushort_t* cache = nullptr;
    if (ws_size >= tier1) { (void)alloc(TOK * DD * 4); S_o = 2; S_f = 2; }
    if (ws_size >= tier2) { (void)alloc(2 * TOK * DD * 4); S_f = 4; }
    if (ws_size >= tier3) { cache = (ushort_t*)alloc(NLL * LSTR * 2); }
    (void)in_sizes; (void)n_in; (void)out_size;

    dim3 tb(32, 8, 1);
    if (cache) {  // pre-transpose ALL weights, batched over layers (grid.z = 4)
        transpose_f2b<<<dim3(24, 24, NLL), tb, 0, stream>>>(Wq, cache,                 DD, DD, DxD, LSTR);
        transpose_f2b<<<dim3(24, 24, NLL), tb, 0, stream>>>(Wk, cache + DD * DD,       DD, DD, DxD, LSTR);
        transpose_f2b<<<dim3(24, 24, NLL), tb, 0, stream>>>(Wv, cache + 2 * DD * DD,   DD, DD, DxD, LSTR);
        transpose_f2b<<<dim3(24, 24, NLL), tb, 0, stream>>>(Wo, cache + 3 * DD * DD,   DD, DD, DxD, LSTR);
        transpose_f2b<<<dim3(96, 24, NLL), tb, 0, stream>>>(W1, cache + 4 * DD * DD,   DD, FF, DxF, LSTR);
        transpose_f2b<<<dim3(24, 96, NLL), tb, 0, stream>>>(W2, cache + 4 * DD * DD + DxF, FF, DD, DxF, LSTR);
    }

    embed_kernel<<<(int)(TOK * DD / 256), 256, 0, stream>>>(word_ids, wemb, hf, hb);

    const int M = (int)TOK; // 4096
    for (int l = 0; l < NLL; ++l) {
        const ushort_t *BtQKV, *BtO, *BtW1, *BtW2;
        if (cache) {
            const ushort_t* base = cache + (size_t)l * LSTR;
            BtQKV = base; BtO = base + 3 * DD * DD;
            BtW1 = base + 4 * DD * DD; BtW2 = base + 4 * DD * DD + DxF;
        } else {
            BtQKV = tw; BtO = tw; BtW1 = tw; BtW2 = tw;
        }
        // fused QKV bias into (dead-at-this-point) pjf
        fuse_bias_kernel<<<9, 256, 0, stream>>>(bq, bk, bv, l, pjf);
        if (!cache) {
            transpose_f2b<<<dim3(24, 24), tb, 0, stream>>>(Wq + (size_t)l * DxD, tw,               DD, DD, 0, 0);
            transpose_f2b<<<dim3(24, 24), tb, 0, stream>>>(Wk + (size_t)l * DxD, tw + DD * DD,     DD, DD, 0, 0);
            transpose_f2b<<<dim3(24, 24), tb, 0, stream>>>(Wv + (size_t)l * DxD, tw + 2 * DD * DD, DD, DD, 0, 0);
        }
        gemm_bf16<<<dim3(QKVS / 128, M / 128, 1), 256, 0, stream>>>(
            hb, BtQKV, pjf, qkv, nullptr, M, QKVS, DD, DD, 0);
        attn_kernel<<<BB * HH * 16, 256, 0, stream>>>(qkv, adjm, etyp, eemb, ao);
        if (!cache)
            transpose_f2b<<<dim3(24, 24), tb, 0, stream>>>(Wo + (size_t)l * DxD, tw, DD, DD, 0, 0);
        gemm_bf16<<<dim3(DD / 128, M / 128, S_o), 256, 0, stream>>>(
            ao, BtO, bo + l * DD, nullptr, pjf, M, DD, DD, DD / S_o, 0);
        ln_kernel<<<M, 256, 0, stream>>>(hf, hb, pjf, S_o, ln1g + l * DD, ln1b + l * DD);
        if (!cache)
            transpose_f2b<<<dim3(96, 24), tb, 0, stream>>>(W1 + (size_t)l * DxF, tw, DD, FF, 0, 0);
        gemm_bf16<<<dim3(FF / 128, M / 128, 1), 256, 0, stream>>>(
            hb, BtW1, b1 + l * FF, ff1, nullptr, M, FF, DD, DD, 1);
        if (!cache)
            transpose_f2b<<<dim3(24, 96), tb, 0, stream>>>(W2 + (size_t)l * DxF, tw, FF, DD, 0, 0);
        gemm_bf16<<<dim3(DD / 128, M / 128, S_f), 256, 0, stream>>>(
            ff1, BtW2, b2 + l * DD, nullptr, pjf, M, DD, FF, FF / S_f, 0);
        ln_kernel<<<M, 256, 0, stream>>>(hf, hb, pjf, S_f, ln2g + l * DD, ln2b + l * DD);
    }
    cls_kernel<<<BB, 256, 0, stream>>>(hf, clsW, clsb, outp);
}